// Round 16
// baseline (193.466 us; speedup 1.0000x reference)
//
#include <hip/hip_runtime.h>

// 2-layer LSTM, B=4096, S=512, F=8, H=10 + FC(10->1) on last step.
// R15 = R10 per-step code byte-identical, re-gridded for balance:
// 683 blocks x 256 thr (2 L0 + 2 L1 waves, 6 elems) -> 1366 blocks x
// 128 thr (1 L0 + 1 L1 wave, 3 elems). Same 2732 waves; blocks/CU
// imbalance 3:2 (1.5x) -> 6:5 (1.2x); cheaper 2-wave barriers.
// Structure: 20-lane element groups (lane l20: gate rows rA=l20, rB=20+l20;
// unified act alpha*rcp(1+exp2(-a))+beta; ig local on i/g lanes; sf,so
// pulled from lane+10 via 2 bperms; c/h on i/g lanes), distance-1 x-dot
// software pipeline, 16-slot h0 buffer, barrier every 8 steps.

typedef __fp16 v2h __attribute__((ext_vector_type(2)));
typedef __fp16 v8h __attribute__((ext_vector_type(8)));
struct h4 { v2h a, b, c, d; };

#define L2E 1.4426950408889634f

__device__ __forceinline__ v2h pkh(float a, float b) {
    return __builtin_amdgcn_cvt_pkrtz(a, b);
}
__device__ __forceinline__ float bpermf(int baddr, float v) {
    int r = __builtin_amdgcn_ds_bpermute(baddr, __builtin_bit_cast(int, v));
    return __builtin_bit_cast(float, r);
}

#define SIGM(a)  __builtin_amdgcn_rcpf(1.0f + __builtin_amdgcn_exp2f(-(a)))
#define TANHP(a) fmaf(-2.0f, __builtin_amdgcn_rcpf(1.0f + __builtin_amdgcn_exp2f(a)), 1.0f)
#define DOT2(acc, w, v) (acc) = __builtin_amdgcn_fdot2((w), (v), (acc), false)

// TBAA-safe packed row read (PTR __fp16*, 16B aligned): 10 halves
#define READROW(PTR, H)                                                      \
    { v8h w0_ = *(const v8h*)(PTR);                                          \
      v2h w1_ = *(const v2h*)((PTR) + 8);                                    \
      h4 q_ = __builtin_bit_cast(h4, w0_);                                   \
      H[0]=q_.a; H[1]=q_.b; H[2]=q_.c; H[3]=q_.d; H[4]=w1_; }

__global__ __launch_bounds__(128, 2)
void lstm2_r15(const float* __restrict__ x,
               const float* __restrict__ hid,
               const float* __restrict__ cel,
               const float* __restrict__ Wih0, const float* __restrict__ Whh0,
               const float* __restrict__ bih0, const float* __restrict__ bhh0,
               const float* __restrict__ Wih1, const float* __restrict__ Whh1,
               const float* __restrict__ bih1, const float* __restrict__ bhh1,
               const float* __restrict__ Wfc,  const float* __restrict__ bfc,
               float* __restrict__ out)
{
    __shared__ __attribute__((aligned(16))) __fp16 h0buf[16][3][24]; // 2.3KB
    __shared__ __attribute__((aligned(16))) __fp16 h1buf[3][24];
    __shared__ float fcb[3][10];

    const int tid  = threadIdx.x;
    const int lane = tid & 63;
    const int uwid = __builtin_amdgcn_readfirstlane(tid >> 6);
    int grp = lane / 20;
    int l20 = lane - grp * 20;
    if (lane >= 60) { grp = 2; l20 = 19; }   // pad lanes duplicate lane 59
    const int  ju       = (l20 < 10) ? l20 : l20 - 10;  // unit index
    const bool unitlane = (l20 < 10);
    const int  eIw = grp;                 // element in block, 0..2
    const int  e   = blockIdx.x * 3 + eIw;   // 1366*3 = 4098 (2 pad)
    const int  ec  = (e < 4095) ? e : 4095;  // clamped for loads
    const int  baddr = ((l20 < 10) ? (lane + 10) : lane) * 4;  // bpermute src

    const float alpha2 = unitlane ? 2.0f : 1.0f;   // rowB act: tanh vs sigma
    const float beta2  = unitlane ? -1.0f : 0.0f;
    const float scB    = unitlane ? 2.0f * L2E : L2E;
    const int   rA = l20, rB = 20 + l20;

    if (uwid == 0) {
        // ================= LAYER-0 (producer) wave =================
        v2h wxA[4], wxB[4], whA[5], whB[5];
        #pragma unroll
        for (int k = 0; k < 4; ++k) {
            wxA[k] = pkh(Wih0[rA*8+2*k]*L2E, Wih0[rA*8+2*k+1]*L2E);
            wxB[k] = pkh(Wih0[rB*8+2*k]*scB, Wih0[rB*8+2*k+1]*scB);
        }
        #pragma unroll
        for (int k = 0; k < 5; ++k) {
            whA[k] = pkh(Whh0[rA*10+2*k]*L2E, Whh0[rA*10+2*k+1]*L2E);
            whB[k] = pkh(Whh0[rB*10+2*k]*scB, Whh0[rB*10+2*k+1]*scB);
        }
        const float bA = (bih0[rA] + bhh0[rA]) * L2E;
        const float bB = (bih0[rB] + bhh0[rB]) * scB;

        v2h hv[5];
        #pragma unroll
        for (int k = 0; k < 5; ++k) hv[k] = pkh(hid[ec*10+2*k], hid[ec*10+2*k+1]);
        float cc = cel[ec * 10 + ju];
        float hj = 0.0f;

        __fp16* const wbase = &h0buf[0][eIw][0];   // slot stride 72 halves
        __fp16* const wlane = wbase + l20;

        const float4* __restrict__ xp = reinterpret_cast<const float4*>(x + (size_t)ec * 4096);
        float4 xb0[2], xb1[2], xb2[2], xb3[2];
        xb0[0]=xp[0]; xb0[1]=xp[1];  xb1[0]=xp[2]; xb1[1]=xp[3];
        xb2[0]=xp[4]; xb2[1]=xp[5];  xb3[0]=xp[6]; xb3[1]=xp[7];

        float axA[2], axB[2];
        // prologue: ax(step 0) from xb0, then refill xb0 <- step 4
        {
            v2h x0=pkh(xb0[0].x,xb0[0].y), x1=pkh(xb0[0].z,xb0[0].w);
            v2h x2=pkh(xb0[1].x,xb0[1].y), x3=pkh(xb0[1].z,xb0[1].w);
            xb0[0]=xp[8]; xb0[1]=xp[9];
            float nA=bA, nB=bB;
            DOT2(nA,wxA[0],x0); DOT2(nB,wxB[0],x0);
            DOT2(nA,wxA[1],x1); DOT2(nB,wxB[1],x1);
            DOT2(nA,wxA[2],x2); DOT2(nB,wxB[2],x2);
            DOT2(nA,wxA[3],x3); DOT2(nB,wxB[3],x3);
            axA[0]=nA; axB[0]=nB;
        }

// L0 step s: filler = ax(s+1) from XB + refill XB; current uses ax[PC];
// write h slot S; packed TBAA-safe readback.
#define L0STEP(S, XB, TN, PC, PN)                                            \
        {                                                                    \
            v2h x0=pkh(XB[0].x,XB[0].y), x1=pkh(XB[0].z,XB[0].w);            \
            v2h x2=pkh(XB[1].x,XB[1].y), x3=pkh(XB[1].z,XB[1].w);            \
            { int tn=(TN)>511?511:(TN); XB[0]=xp[2*tn]; XB[1]=xp[2*tn+1]; }  \
            float nA=bA, nB=bB;                                              \
            DOT2(nA,wxA[0],x0); DOT2(nB,wxB[0],x0);                          \
            DOT2(nA,wxA[1],x1); DOT2(nB,wxB[1],x1);                          \
            DOT2(nA,wxA[2],x2); DOT2(nB,wxB[2],x2);                          \
            DOT2(nA,wxA[3],x3); DOT2(nB,wxB[3],x3);                          \
            axA[PN]=nA; axB[PN]=nB;                                          \
            float aA=axA[PC], aB=axB[PC];                                    \
            DOT2(aA,whA[0],hv[0]); DOT2(aB,whB[0],hv[0]);                    \
            DOT2(aA,whA[1],hv[1]); DOT2(aB,whB[1],hv[1]);                    \
            DOT2(aA,whA[2],hv[2]); DOT2(aB,whB[2],hv[2]);                    \
            DOT2(aA,whA[3],hv[3]); DOT2(aB,whB[3],hv[3]);                    \
            DOT2(aA,whA[4],hv[4]); DOT2(aB,whB[4],hv[4]);                    \
            float r1 = SIGM(aA);                                             \
            float r2 = __builtin_amdgcn_rcpf(1.0f + __builtin_amdgcn_exp2f(-aB)); \
            float act2 = fmaf(alpha2, r2, beta2);                            \
            float ig = r1 * act2;                                            \
            float sf = bpermf(baddr, r1);                                    \
            float so = bpermf(baddr, act2);                                  \
            cc = fmaf(sf, cc, ig);                                           \
            hj = so * TANHP((2.0f*L2E) * cc);                                \
            wlane[(S)*72] = (__fp16)hj;                                      \
            READROW(wbase + (S)*72, hv)                                      \
        }

        for (int it = 0; it < 32; ++it) {
            const int tb = 16 * it;
            L0STEP(0,  xb1, tb+5,  0, 1)
            L0STEP(1,  xb2, tb+6,  1, 0)
            L0STEP(2,  xb3, tb+7,  0, 1)
            L0STEP(3,  xb0, tb+8,  1, 0)
            L0STEP(4,  xb1, tb+9,  0, 1)
            L0STEP(5,  xb2, tb+10, 1, 0)
            L0STEP(6,  xb3, tb+11, 0, 1)
            L0STEP(7,  xb0, tb+12, 1, 0)
            __syncthreads();
            L0STEP(8,  xb1, tb+13, 0, 1)
            L0STEP(9,  xb2, tb+14, 1, 0)
            L0STEP(10, xb3, tb+15, 0, 1)
            L0STEP(11, xb0, tb+16, 1, 0)
            L0STEP(12, xb1, tb+17, 0, 1)
            L0STEP(13, xb2, tb+18, 1, 0)
            L0STEP(14, xb3, tb+19, 0, 1)
            L0STEP(15, xb0, tb+20, 1, 0)
            __syncthreads();
        }
#undef L0STEP

        __syncthreads();   // pair with L1's FC epilogue barrier
        if (unitlane && e < 4096) {
            out[4096          + e * 10 + ju] = hj;   // h0_T
            out[4096 + 81920  + e * 10 + ju] = cc;   // c0_T
        }

    } else {
        // ================= LAYER-1 (consumer) wave =================
        v2h wiA[5], wiB[5], whA[5], whB[5];
        #pragma unroll
        for (int k = 0; k < 5; ++k) {
            wiA[k] = pkh(Wih1[rA*10+2*k]*L2E, Wih1[rA*10+2*k+1]*L2E);
            wiB[k] = pkh(Wih1[rB*10+2*k]*scB, Wih1[rB*10+2*k+1]*scB);
            whA[k] = pkh(Whh1[rA*10+2*k]*L2E, Whh1[rA*10+2*k+1]*L2E);
            whB[k] = pkh(Whh1[rB*10+2*k]*scB, Whh1[rB*10+2*k+1]*scB);
        }
        const float bA = (bih1[rA] + bhh1[rA]) * L2E;
        const float bB = (bih1[rB] + bhh1[rB]) * scB;
        const float wfc = Wfc[ju];

        v2h hv[5];
        #pragma unroll
        for (int k = 0; k < 5; ++k) hv[k] = pkh(hid[40960+ec*10+2*k], hid[40960+ec*10+2*k+1]);
        float cc = cel[40960 + ec * 10 + ju];
        float hj = 0.0f;

        const __fp16* const rbase = &h0buf[0][eIw][0];   // slot stride 72 halves
        __fp16* const h1w  = &h1buf[eIw][0];
        __fp16* const h1wl = h1w + l20;

        float axA[2], axB[2];

// input-dots (bias + 5 dots x2) for slot S -> ax parity P
#define L1PRE(S, P)                                                          \
        {                                                                    \
            v2h pr[5];                                                       \
            READROW(rbase + (S)*72, pr)                                      \
            float nA=bA, nB=bB;                                              \
            DOT2(nA,wiA[0],pr[0]); DOT2(nB,wiB[0],pr[0]);                    \
            DOT2(nA,wiA[1],pr[1]); DOT2(nB,wiB[1],pr[1]);                    \
            DOT2(nA,wiA[2],pr[2]); DOT2(nB,wiB[2],pr[2]);                    \
            DOT2(nA,wiA[3],pr[3]); DOT2(nB,wiB[3],pr[3]);                    \
            DOT2(nA,wiA[4],pr[4]); DOT2(nB,wiB[4],pr[4]);                    \
            axA[P]=nA; axB[P]=nB;                                            \
        }

// current step using ax parity PC: h-dots, acts, c/h, h1 write+readback
#define L1CORE(PC)                                                           \
        {                                                                    \
            float aA=axA[PC], aB=axB[PC];                                    \
            DOT2(aA,whA[0],hv[0]); DOT2(aB,whB[0],hv[0]);                    \
            DOT2(aA,whA[1],hv[1]); DOT2(aB,whB[1],hv[1]);                    \
            DOT2(aA,whA[2],hv[2]); DOT2(aB,whB[2],hv[2]);                    \
            DOT2(aA,whA[3],hv[3]); DOT2(aB,whB[3],hv[3]);                    \
            DOT2(aA,whA[4],hv[4]); DOT2(aB,whB[4],hv[4]);                    \
            float r1 = SIGM(aA);                                             \
            float r2 = __builtin_amdgcn_rcpf(1.0f + __builtin_amdgcn_exp2f(-aB)); \
            float act2 = fmaf(alpha2, r2, beta2);                            \
            float ig = r1 * act2;                                            \
            float sf = bpermf(baddr, r1);                                    \
            float so = bpermf(baddr, act2);                                  \
            cc = fmaf(sf, cc, ig);                                           \
            hj = so * TANHP((2.0f*L2E) * cc);                                \
            h1wl[0] = (__fp16)hj;                                            \
            READROW(h1w, hv)                                                 \
        }

        for (int it = 0; it < 32; ++it) {
            __syncthreads();
            L1PRE(0, 0)
            L1PRE(1, 1) L1CORE(0)
            L1PRE(2, 0) L1CORE(1)
            L1PRE(3, 1) L1CORE(0)
            L1PRE(4, 0) L1CORE(1)
            L1PRE(5, 1) L1CORE(0)
            L1PRE(6, 0) L1CORE(1)
            L1PRE(7, 1) L1CORE(0)
            L1CORE(1)
            __syncthreads();
            L1PRE(8, 0)
            L1PRE(9,  1) L1CORE(0)
            L1PRE(10, 0) L1CORE(1)
            L1PRE(11, 1) L1CORE(0)
            L1PRE(12, 0) L1CORE(1)
            L1PRE(13, 1) L1CORE(0)
            L1PRE(14, 0) L1CORE(1)
            L1PRE(15, 1) L1CORE(0)
            L1CORE(1)
        }
#undef L1PRE
#undef L1CORE

        if (unitlane) fcb[eIw][ju] = hj * wfc;
        __syncthreads();
        if (l20 == 0 && e < 4096) {
            float p = bfc[0];
            #pragma unroll
            for (int k = 0; k < 10; ++k) p += fcb[eIw][k];
            out[e] = p;
        }
        if (unitlane && e < 4096) {
            out[4096 + 40960  + e * 10 + ju] = hj;   // h1_T
            out[4096 + 122880 + e * 10 + ju] = cc;   // c1_T
        }
    }
}

extern "C" void kernel_launch(void* const* d_in, const int* in_sizes, int n_in,
                              void* d_out, int out_size, void* d_ws, size_t ws_size,
                              hipStream_t stream) {
    const float* x    = (const float*)d_in[0];
    const float* hid  = (const float*)d_in[1];
    const float* cel  = (const float*)d_in[2];
    const float* Wih0 = (const float*)d_in[3];
    const float* Whh0 = (const float*)d_in[4];
    const float* bih0 = (const float*)d_in[5];
    const float* bhh0 = (const float*)d_in[6];
    const float* Wih1 = (const float*)d_in[7];
    const float* Whh1 = (const float*)d_in[8];
    const float* bih1 = (const float*)d_in[9];
    const float* bhh1 = (const float*)d_in[10];
    const float* Wfc  = (const float*)d_in[11];
    const float* bfc  = (const float*)d_in[12];

    // 1366 blocks x 128 thr (1 L0 wave + 1 L1 wave, 3 elements/block)
    hipLaunchKernelGGL(lstm2_r15, dim3(1366), dim3(128), 0, stream,
                       x, hid, cel, Wih0, Whh0, bih0, bhh0,
                       Wih1, Whh1, bih1, bhh1, Wfc, bfc,
                       (float*)d_out);
}